// Round 3
// baseline (177.164 us; speedup 1.0000x reference)
//
#include <hip/hip_runtime.h>
#include <math.h>

// PyramidROIAlign: B=2, N=1000, C=256, POOL=7x7
// p3: [2,128,128,256], p4: [2,64,64,256], p5: [2,32,32,256], all fp32 NHWC.
// Output: [2,1000,7,7,256] fp32.
//
// R5: locality pass. R4 counters showed FETCH_SIZE 142 MB vs 44 MB unique
// feature bytes (~3.2x over-fetch): random box order scatters concurrent
// blocks across 8 non-coherent XCD L2s, and the harness's 401 MB poison
// fill flushes L3 between iterations, so inter-box reuse is never captured.
// Fix: a ~5us counting-sort pre-kernel buckets boxes by
// (level, batch, y-band) into a permutation (d_ws), and the main kernel
// maps block -> perm[xcd_chunked(bid)] so each XCD processes a contiguous
// run of spatially-adjacent same-level boxes (one p3 y-band ~2 MB fits a
// 4 MB XCD L2). Output is still written at the ORIGINAL box index ->
// bit-identical results regardless of permutation order.
// Also reverted R4's nontemporal stores (WRITE_SIZE was already 98 MB to
// HBM without them; they bought nothing and possibly cost ~2us).
//
// Main kernel mapping (unchanged from R4): one block (448 thr = 7 waves)
// per box; wave = pool row iy; lane covers 4 channels (vec4).
// Three-phase body: (1) all column indices/weights, (2) all 28 vec4 corner
// loads issued back-to-back (max MLP), (3) blend + store.

#define N_PER_B 1000
#define NBOX    2000   // B*N
#define CCH     256
#define PH      7
#define PW      7

#define NXCD    8
#define CHUNK   (NBOX / NXCD)   // 250

// buckets: ((level-3)*2 + batch)*16 + yband  -> 3*2*16 = 96
#define NBUCKET 96

typedef float f4 __attribute__((ext_vector_type(4)));

__device__ __forceinline__ int box_level(float h, float w) {
    // roi_level = clip(ceil(5 + log(h*w)/log(2)), 3, 5) -- match ref op order
    const float lvl  = ceilf(5.0f + logf(h * w) / 0.69314718055994530942f);
    const float lvlc = fminf(fmaxf(lvl, 3.0f), 5.0f);
    return (int)lvlc;
}

// ---------------- sort pre-kernel: counting sort into perm ----------------
__global__ __launch_bounds__(1024) void sort_boxes_kernel(
    const float* __restrict__ boxes, int* __restrict__ perm)
{
    __shared__ int cnt[NBUCKET];
    __shared__ int base[NBUCKET];
    const int t = threadIdx.x;
    if (t < NBUCKET) cnt[t] = 0;
    __syncthreads();

    int mykey[2];
#pragma unroll
    for (int i = 0; i < 2; ++i) {
        const int box = t + i * 1024;
        int key = -1;
        if (box < NBOX) {
            const float y1 = boxes[box * 4 + 0];
            const float x1 = boxes[box * 4 + 1];
            const float y2 = boxes[box * 4 + 2];
            const float x2 = boxes[box * 4 + 3];
            const int level = box_level(y2 - y1, x2 - x1);
            const int b     = (box >= N_PER_B) ? 1 : 0;
            const float cy  = 0.5f * (y1 + y2);   // normalized box center
            const int yband = (int)fminf(fmaxf(cy * 16.0f, 0.0f), 15.0f);
            key = ((level - 3) * 2 + b) * 16 + yband;
            atomicAdd(&cnt[key], 1);
        }
        mykey[i] = key;
    }
    __syncthreads();
    if (t == 0) {
        int acc = 0;
        for (int k = 0; k < NBUCKET; ++k) { base[k] = acc; acc += cnt[k]; }
    }
    __syncthreads();
#pragma unroll
    for (int i = 0; i < 2; ++i) {
        const int box = t + i * 1024;
        if (box < NBOX) {
            const int pos = atomicAdd(&base[mykey[i]], 1);
            perm[pos] = box;
        }
    }
}

// ---------------- main kernel ----------------
__global__ __launch_bounds__(448, 2) void pyramid_roi_align_kernel(
    const float* __restrict__ boxes,   // [2000,4] y1,x1,y2,x2
    const float* __restrict__ p3,      // [2,128,128,256]
    const float* __restrict__ p4,      // [2,64,64,256]
    const float* __restrict__ p5,      // [2,32,32,256]
    const int*   __restrict__ perm,    // [2000] sorted box order (or null)
    float* __restrict__ out)           // [2000,49,256]
{
    const int bid = blockIdx.x;
    // XCD-chunked swizzle: blockIdx round-robins across XCDs, so give
    // XCD k the contiguous sorted range [k*CHUNK, (k+1)*CHUNK).
    const int swz = (bid & (NXCD - 1)) * CHUNK + (bid >> 3);
    const int box = perm ? perm[swz] : swz;

    const int iy   = threadIdx.x >> 6;   // wave id = pool row, 0..6
    const int lane = threadIdx.x & 63;
    const int c    = lane * 4;

    // ---- per-box setup (wave-uniform) ----
    const float y1 = boxes[box * 4 + 0];
    const float x1 = boxes[box * 4 + 1];
    const float y2 = boxes[box * 4 + 2];
    const float x2 = boxes[box * 4 + 3];
    const float h  = y2 - y1;
    const float w  = x2 - x1;

    const int level = box_level(h, w);

    const float* feat;
    int H;
    if (level <= 3)      { feat = p3; H = 128; }
    else if (level == 4) { feat = p4; H = 64;  }
    else                 { feat = p5; H = 32;  }
    const int W = H;

    const int b = (box >= N_PER_B) ? 1 : 0;
    feat += (size_t)b * H * W * CCH;

    const float Hm1 = (float)(H - 1);
    const float Wm1 = (float)(W - 1);

    // ys = y1*(H-1) + iy * ((y2-y1)*(H-1)/6)   (match reference exactly)
    const float ys = y1 * Hm1 + (float)iy * (h * Hm1 / 6.0f);
    const bool  vy = (ys >= 0.0f) && (ys <= Hm1);

    const float y0f = floorf(ys);
    const float wy  = ys - y0f;
    const float omwy = 1.0f - wy;

    const int y0i = (int)fminf(fmaxf(y0f,        0.0f), Hm1);
    const int y1i = (int)fminf(fmaxf(y0f + 1.0f, 0.0f), Hm1);

    const float* row0 = feat + (size_t)y0i * W * CCH + c;  // top row
    const float* row1 = feat + (size_t)y1i * W * CCH + c;  // bottom row

    const float xstep = w * Wm1 / 6.0f;

    // ---- phase 1: all column indices / weights (no memory ops) ----
    int   x0i[PW], x1i[PW];
    float wxv[PW];
    bool  vx[PW];
#pragma unroll
    for (int ix = 0; ix < PW; ++ix) {
        const float xs = x1 * Wm1 + (float)ix * xstep;
        vx[ix] = (xs >= 0.0f) && (xs <= Wm1);
        const float x0f = floorf(xs);
        wxv[ix] = xs - x0f;
        x0i[ix] = (int)fminf(fmaxf(x0f,        0.0f), Wm1);
        x1i[ix] = (int)fminf(fmaxf(x0f + 1.0f, 0.0f), Wm1);
    }

    // ---- phase 2: issue ALL 28 corner loads (max MLP) ----
    f4 v00[PW], v01[PW], v10[PW], v11[PW];
#pragma unroll
    for (int ix = 0; ix < PW; ++ix) {
        v00[ix] = *(const f4*)(row0 + (size_t)x0i[ix] * CCH);
        v01[ix] = *(const f4*)(row0 + (size_t)x1i[ix] * CCH);
        v10[ix] = *(const f4*)(row1 + (size_t)x0i[ix] * CCH);
        v11[ix] = *(const f4*)(row1 + (size_t)x1i[ix] * CCH);
    }

    float* dst_base = out + ((size_t)box * (PH * PW) + (size_t)iy * PW) * CCH + c;

    // ---- phase 3: blend + store ----
#pragma unroll
    for (int ix = 0; ix < PW; ++ix) {
        const float wx   = wxv[ix];
        const float omwx = 1.0f - wx;

        f4 res = (v00[ix] * omwx + v01[ix] * wx) * omwy
               + (v10[ix] * omwx + v11[ix] * wx) * wy;

        if (!(vy && vx[ix])) res = (f4)(0.0f);

        *(f4*)(dst_base + (size_t)ix * CCH) = res;
    }
}

extern "C" void kernel_launch(void* const* d_in, const int* in_sizes, int n_in,
                              void* d_out, int out_size, void* d_ws, size_t ws_size,
                              hipStream_t stream) {
    const float* boxes = (const float*)d_in[0];
    // d_in[1] = positive_indices (unused by reference)
    const float* p3 = (const float*)d_in[2];
    const float* p4 = (const float*)d_in[3];
    const float* p5 = (const float*)d_in[4];
    // d_in[5] = config (unused)
    float* out = (float*)d_out;

    int* perm = nullptr;
    if (d_ws != nullptr && ws_size >= (size_t)NBOX * sizeof(int)) {
        perm = (int*)d_ws;
        hipLaunchKernelGGL(sort_boxes_kernel, dim3(1), dim3(1024), 0, stream,
                           boxes, perm);
    }

    hipLaunchKernelGGL(pyramid_roi_align_kernel, dim3(NBOX), dim3(448), 0, stream,
                       boxes, p3, p4, p5, perm, out);
}

// Round 4
// 171.271 us; speedup vs baseline: 1.0344x; 1.0344x over previous
//
#include <hip/hip_runtime.h>
#include <math.h>

// PyramidROIAlign: B=2, N=1000, C=256, POOL=7x7
// p3: [2,128,128,256], p4: [2,64,64,256], p5: [2,32,32,256], all fp32 NHWC.
// Output: [2,1000,7,7,256] fp32.
//
// R6: R5 post-mortem showed the sort WORKS (FETCH 142->85 MB) but the
// static per-XCD chunk swizzle created level imbalance: XCDs that drew
// all-level-3 chunks (scattered reads over 16.8 MB p3) ran long while
// level-5 XCDs (2.1 MB L2-resident p5) idled -> OccupancyPercent 14.7%,
// dur 60->65us. Fix: box = perm[blockIdx.x] DIRECTLY. Consecutive bids
// round-robin across XCDs in dispatch-time order, so all 8 XCDs sweep the
// sorted (level, batch, y-band) sequence together: chip-wide temporal
// locality (L3 absorbs cross-XCD duplication), and load balance is
// automatic (no static quota per XCD).
// Output is written at the ORIGINAL box index -> results identical.
//
// Main kernel mapping (unchanged): one block (448 thr = 7 waves) per box;
// wave = pool row iy; lane covers 4 channels (vec4). Three-phase body:
// (1) all column indices/weights, (2) all 28 vec4 corner loads issued
// back-to-back (max MLP), (3) blend + store.

#define N_PER_B 1000
#define NBOX    2000   // B*N
#define CCH     256
#define PH      7
#define PW      7

// buckets: ((level-3)*2 + batch)*16 + yband  -> 3*2*16 = 96
#define NBUCKET 96

typedef float f4 __attribute__((ext_vector_type(4)));

__device__ __forceinline__ int box_level(float h, float w) {
    // roi_level = clip(ceil(5 + log(h*w)/log(2)), 3, 5) -- match ref op order
    const float lvl  = ceilf(5.0f + logf(h * w) / 0.69314718055994530942f);
    const float lvlc = fminf(fmaxf(lvl, 3.0f), 5.0f);
    return (int)lvlc;
}

// ---------------- sort pre-kernel: counting sort into perm ----------------
__global__ __launch_bounds__(1024) void sort_boxes_kernel(
    const float* __restrict__ boxes, int* __restrict__ perm)
{
    __shared__ int cnt[NBUCKET];
    __shared__ int base[NBUCKET];
    const int t = threadIdx.x;
    if (t < NBUCKET) cnt[t] = 0;
    __syncthreads();

    int mykey[2];
#pragma unroll
    for (int i = 0; i < 2; ++i) {
        const int box = t + i * 1024;
        int key = -1;
        if (box < NBOX) {
            const float y1 = boxes[box * 4 + 0];
            const float x1 = boxes[box * 4 + 1];
            const float y2 = boxes[box * 4 + 2];
            const float x2 = boxes[box * 4 + 3];
            const int level = box_level(y2 - y1, x2 - x1);
            const int b     = (box >= N_PER_B) ? 1 : 0;
            const float cy  = 0.5f * (y1 + y2);   // normalized box center
            const int yband = (int)fminf(fmaxf(cy * 16.0f, 0.0f), 15.0f);
            key = ((level - 3) * 2 + b) * 16 + yband;
            atomicAdd(&cnt[key], 1);
        }
        mykey[i] = key;
    }
    __syncthreads();
    if (t == 0) {
        int acc = 0;
        for (int k = 0; k < NBUCKET; ++k) { base[k] = acc; acc += cnt[k]; }
    }
    __syncthreads();
#pragma unroll
    for (int i = 0; i < 2; ++i) {
        const int box = t + i * 1024;
        if (box < NBOX) {
            const int pos = atomicAdd(&base[mykey[i]], 1);
            perm[pos] = box;
        }
    }
}

// ---------------- main kernel ----------------
__global__ __launch_bounds__(448, 2) void pyramid_roi_align_kernel(
    const float* __restrict__ boxes,   // [2000,4] y1,x1,y2,x2
    const float* __restrict__ p3,      // [2,128,128,256]
    const float* __restrict__ p4,      // [2,64,64,256]
    const float* __restrict__ p5,      // [2,32,32,256]
    const int*   __restrict__ perm,    // [2000] sorted box order (or null)
    float* __restrict__ out)           // [2000,49,256]
{
    // Direct sorted order: consecutive bids are dispatched round-robin
    // across XCDs in time order, so the whole chip sweeps the sorted
    // sequence together (chip-wide temporal locality + auto load balance).
    const int bid = blockIdx.x;
    const int box = perm ? perm[bid] : bid;

    const int iy   = threadIdx.x >> 6;   // wave id = pool row, 0..6
    const int lane = threadIdx.x & 63;
    const int c    = lane * 4;

    // ---- per-box setup (wave-uniform) ----
    const float y1 = boxes[box * 4 + 0];
    const float x1 = boxes[box * 4 + 1];
    const float y2 = boxes[box * 4 + 2];
    const float x2 = boxes[box * 4 + 3];
    const float h  = y2 - y1;
    const float w  = x2 - x1;

    const int level = box_level(h, w);

    const float* feat;
    int H;
    if (level <= 3)      { feat = p3; H = 128; }
    else if (level == 4) { feat = p4; H = 64;  }
    else                 { feat = p5; H = 32;  }
    const int W = H;

    const int b = (box >= N_PER_B) ? 1 : 0;
    feat += (size_t)b * H * W * CCH;

    const float Hm1 = (float)(H - 1);
    const float Wm1 = (float)(W - 1);

    // ys = y1*(H-1) + iy * ((y2-y1)*(H-1)/6)   (match reference exactly)
    const float ys = y1 * Hm1 + (float)iy * (h * Hm1 / 6.0f);
    const bool  vy = (ys >= 0.0f) && (ys <= Hm1);

    const float y0f = floorf(ys);
    const float wy  = ys - y0f;
    const float omwy = 1.0f - wy;

    const int y0i = (int)fminf(fmaxf(y0f,        0.0f), Hm1);
    const int y1i = (int)fminf(fmaxf(y0f + 1.0f, 0.0f), Hm1);

    const float* row0 = feat + (size_t)y0i * W * CCH + c;  // top row
    const float* row1 = feat + (size_t)y1i * W * CCH + c;  // bottom row

    const float xstep = w * Wm1 / 6.0f;

    // ---- phase 1: all column indices / weights (no memory ops) ----
    int   x0i[PW], x1i[PW];
    float wxv[PW];
    bool  vx[PW];
#pragma unroll
    for (int ix = 0; ix < PW; ++ix) {
        const float xs = x1 * Wm1 + (float)ix * xstep;
        vx[ix] = (xs >= 0.0f) && (xs <= Wm1);
        const float x0f = floorf(xs);
        wxv[ix] = xs - x0f;
        x0i[ix] = (int)fminf(fmaxf(x0f,        0.0f), Wm1);
        x1i[ix] = (int)fminf(fmaxf(x0f + 1.0f, 0.0f), Wm1);
    }

    // ---- phase 2: issue ALL 28 corner loads (max MLP) ----
    f4 v00[PW], v01[PW], v10[PW], v11[PW];
#pragma unroll
    for (int ix = 0; ix < PW; ++ix) {
        v00[ix] = *(const f4*)(row0 + (size_t)x0i[ix] * CCH);
        v01[ix] = *(const f4*)(row0 + (size_t)x1i[ix] * CCH);
        v10[ix] = *(const f4*)(row1 + (size_t)x0i[ix] * CCH);
        v11[ix] = *(const f4*)(row1 + (size_t)x1i[ix] * CCH);
    }

    float* dst_base = out + ((size_t)box * (PH * PW) + (size_t)iy * PW) * CCH + c;

    // ---- phase 3: blend + store ----
#pragma unroll
    for (int ix = 0; ix < PW; ++ix) {
        const float wx   = wxv[ix];
        const float omwx = 1.0f - wx;

        f4 res = (v00[ix] * omwx + v01[ix] * wx) * omwy
               + (v10[ix] * omwx + v11[ix] * wx) * wy;

        if (!(vy && vx[ix])) res = (f4)(0.0f);

        *(f4*)(dst_base + (size_t)ix * CCH) = res;
    }
}

extern "C" void kernel_launch(void* const* d_in, const int* in_sizes, int n_in,
                              void* d_out, int out_size, void* d_ws, size_t ws_size,
                              hipStream_t stream) {
    const float* boxes = (const float*)d_in[0];
    // d_in[1] = positive_indices (unused by reference)
    const float* p3 = (const float*)d_in[2];
    const float* p4 = (const float*)d_in[3];
    const float* p5 = (const float*)d_in[4];
    // d_in[5] = config (unused)
    float* out = (float*)d_out;

    int* perm = nullptr;
    if (d_ws != nullptr && ws_size >= (size_t)NBOX * sizeof(int)) {
        perm = (int*)d_ws;
        hipLaunchKernelGGL(sort_boxes_kernel, dim3(1), dim3(1024), 0, stream,
                           boxes, perm);
    }

    hipLaunchKernelGGL(pyramid_roi_align_kernel, dim3(NBOX), dim3(448), 0, stream,
                       boxes, p3, p4, p5, perm, out);
}